// Round 5
// baseline (359.053 us; speedup 1.0000x reference)
//
#include <hip/hip_runtime.h>

#define NB 32
#define NL 512
#define ND 512
#define NH 1024
#define NE 8
#define NROWS (NB * NL)       // 16384
#define CW 2048               // C width = [U|V]

typedef __attribute__((ext_vector_type(8))) short bf16x8;
typedef __attribute__((ext_vector_type(4))) float f32x4;

__device__ __forceinline__ unsigned short f2bf(float f) {
    unsigned u = __float_as_uint(f);
    return (unsigned short)((u + 0x7fffu + ((u >> 16) & 1u)) >> 16);
}
__device__ __forceinline__ float bf2f(unsigned short b) {
    return __uint_as_float(((unsigned)b) << 16);
}
__device__ __forceinline__ unsigned pkhi(float a, float b) {
    return (unsigned)f2bf(a) | ((unsigned)f2bf(b) << 16);
}

// ---------- W prep: transpose + split, packed [ntg 0..127][kb 0..15][lane][jp] ----------
// ntg 0..63 = Wt, 64..127 = Ws.  hi at bpack[0..524287], lo at +524288.
__global__ __launch_bounds__(256) void wprep(
    const float* __restrict__ Wt, const float* __restrict__ Ws,
    unsigned* __restrict__ bpack)
{
    __shared__ float tile[64][65];
    int bid = blockIdx.x;
    int mat = bid >> 7, rem = bid & 127;
    int kt0 = (rem >> 4) << 6;   // 0..448
    int nt0 = (rem & 15) << 6;   // 0..960
    const float* W = mat ? Ws : Wt;
    unsigned* Oh = bpack;
    unsigned* Ol = bpack + 524288u;
    int t = threadIdx.x;
    #pragma unroll
    for (int i = 0; i < 16; ++i) {
        int idx = t + 256 * i;
        int k = idx >> 6, n = idx & 63;
        tile[k][n] = W[(size_t)(kt0 + k) * NH + nt0 + n];
    }
    __syncthreads();
    #pragma unroll
    for (int i = 0; i < 8; ++i) {
        int idx = t + 256 * i;                 // 2048 u32 positions
        int jp = idx & 3, lane = (idx >> 2) & 63, kbr = (idx >> 8) & 1, ntr = (idx >> 9) & 3;
        int ncol = ntr * 16 + (lane & 15);
        int kcol = kbr * 32 + ((lane >> 4) << 3) + jp * 2;
        float w0 = tile[kcol][ncol], w1 = tile[kcol + 1][ncol];
        unsigned short h0 = f2bf(w0), h1 = f2bf(w1);
        unsigned short l0 = f2bf(w0 - bf2f(h0)), l1 = f2bf(w1 - bf2f(h1));
        int ntg = mat * 64 + (nt0 >> 4) + ntr;
        int kb = (kt0 >> 5) + kbr;
        unsigned offs = ((unsigned)(ntg * 16 + kb) * 64u + (unsigned)lane) * 4u + jp;
        Oh[offs] = (unsigned)h0 | ((unsigned)h1 << 16);
        Ol[offs] = (unsigned)l0 | ((unsigned)l1 << 16);
    }
}

// ---------- stage 1: C = x @ [Wt|Ws]  (bf16 out; exact tiles get lo residual) ----------
__global__ __launch_bounds__(256) void gemm_uv(
    const float* __restrict__ x, const unsigned* __restrict__ bpack,
    unsigned short* __restrict__ C, unsigned short* __restrict__ Clo)
{
    __shared__ union {
        struct { unsigned Ah[4 * 64 * 4]; unsigned Al[4 * 64 * 4]; } a;  // 4+4 KB
        unsigned short cs[64][272];                                      // 34.8 KB
    } sm;

    const int tid = threadIdx.x, lane = tid & 63, wave = tid >> 6;
    const int g = lane >> 4, c = lane & 15;

    // XCD-aware swizzle: each XCD owns a 64-mi chunk x 4-ni half
    int bid = blockIdx.x;
    int xcd = bid & 7, kk = bid >> 3;
    int mi = (kk >> 2) + ((xcd >> 1) << 6);   // 0..255
    int ni = (kk & 3) + ((xcd & 1) << 2);     // 0..7
    const bool exact = (mi & 7) == 0;
    const int m0 = mi * 64;

    const unsigned* Bhi = bpack;
    const unsigned* Blo = bpack + 524288u;

    f32x4 acc[4][4];
    #pragma unroll
    for (int nf = 0; nf < 4; ++nf)
        #pragma unroll
        for (int mf = 0; mf < 4; ++mf) acc[nf][mf] = (f32x4){0.f, 0.f, 0.f, 0.f};

    const int rA = tid >> 3, cA = tid & 7;          // idx = tid   : rows 0..31
    const int rB = (tid + 256) >> 3;                // idx = tid+256: rows 32..63

    auto ldx4 = [&](int kb, int row, int c4) -> float4 {
        return *(const float4*)&x[(size_t)(m0 + row) * ND + kb * 32 + c4 * 4];
    };
    auto cvw = [&](float4 v, int row, int c4) {
        int base = ((row >> 4) * 64 + (c4 >> 1) * 16 + (row & 15)) * 4 + (c4 & 1) * 2;
        if (exact) {
            unsigned short h0 = f2bf(v.x), h1 = f2bf(v.y), h2 = f2bf(v.z), h3 = f2bf(v.w);
            sm.a.Ah[base]     = (unsigned)h0 | ((unsigned)h1 << 16);
            sm.a.Ah[base + 1] = (unsigned)h2 | ((unsigned)h3 << 16);
            sm.a.Al[base]     = pkhi(v.x - bf2f(h0), v.y - bf2f(h1));
            sm.a.Al[base + 1] = pkhi(v.z - bf2f(h2), v.w - bf2f(h3));
        } else {
            sm.a.Ah[base]     = pkhi(v.x, v.y);
            sm.a.Ah[base + 1] = pkhi(v.z, v.w);
        }
    };

    float4 xa = ldx4(0, rA, cA), xb = ldx4(0, rB, cA);

    for (int kb = 0; kb < 16; ++kb) {
        __syncthreads();
        cvw(xa, rA, cA);
        cvw(xb, rB, cA);
        int kn = kb + 1 < 16 ? kb + 1 : 15;
        xa = ldx4(kn, rA, cA);
        xb = ldx4(kn, rB, cA);
        __syncthreads();

        const int nterm = exact ? 3 : 1;
        for (int t = 0; t < nterm; ++t) {
            const unsigned* As = (t == 1) ? sm.a.Al : sm.a.Ah;
            const unsigned* Bs = (t == 2) ? Blo : Bhi;
            bf16x8 af[4], bfr[4];
            #pragma unroll
            for (int mf = 0; mf < 4; ++mf)
                af[mf] = *(const bf16x8*)(As + (mf * 64 + lane) * 4);
            #pragma unroll
            for (int nf = 0; nf < 4; ++nf) {
                int nt = ni * 16 + wave * 4 + nf;
                bfr[nf] = *(const bf16x8*)(Bs + ((unsigned)(nt * 16 + kb) * 64u + (unsigned)lane) * 4u);
            }
            #pragma unroll
            for (int nf = 0; nf < 4; ++nf)
                #pragma unroll
                for (int mf = 0; mf < 4; ++mf)
                    acc[nf][mf] = __builtin_amdgcn_mfma_f32_16x16x32_bf16(af[mf], bfr[nf], acc[nf][mf], 0, 0, 0);
        }
    }

    // ---- store C (hi) through LDS, coalesced ----
    __syncthreads();
    #pragma unroll
    for (int nf = 0; nf < 4; ++nf)
        #pragma unroll
        for (int mf = 0; mf < 4; ++mf)
            #pragma unroll
            for (int r = 0; r < 4; ++r)
                sm.cs[mf * 16 + g * 4 + r][wave * 64 + nf * 16 + c] = f2bf(acc[nf][mf][r]);
    __syncthreads();
    #pragma unroll
    for (int i = 0; i < 8; ++i) {
        int idx = tid + 256 * i;
        int row = idx >> 5, cg = idx & 31;
        *(uint4*)&C[(size_t)(m0 + row) * CW + ni * 256 + cg * 8] = *(const uint4*)&sm.cs[row][cg * 8];
    }
    if (exact) {
        __syncthreads();
        #pragma unroll
        for (int nf = 0; nf < 4; ++nf)
            #pragma unroll
            for (int mf = 0; mf < 4; ++mf)
                #pragma unroll
                for (int r = 0; r < 4; ++r) {
                    float v = acc[nf][mf][r];
                    sm.cs[mf * 16 + g * 4 + r][wave * 64 + nf * 16 + c] = f2bf(v - bf2f(f2bf(v)));
                }
        __syncthreads();
        int bq = mi >> 3;   // batch index
        #pragma unroll
        for (int i = 0; i < 3; ++i) {
            int idx = tid + 256 * i;
            int row = idx >> 5, cg = idx & 31;
            if (row < 20)
                *(uint4*)&Clo[((size_t)bq * 20 + row) * CW + ni * 256 + cg * 8] = *(const uint4*)&sm.cs[row][cg * 8];
        }
    }
}

// ---------- stage 2: MA decomp + LN + med + logits + softmax/top2 ----------
__global__ __launch_bounds__(1024) void stage2(
    const unsigned short* __restrict__ C, const unsigned short* __restrict__ Clo,
    const float* __restrict__ bt, const float* __restrict__ gt, const float* __restrict__ bet,
    const float* __restrict__ bs, const float* __restrict__ gs, const float* __restrict__ bes,
    const float* __restrict__ W2, const float* __restrict__ b2,
    unsigned* __restrict__ mb, float* __restrict__ gates)
{
    __shared__ unsigned short stg[2][88][132];   // 46.5 KB
    __shared__ float exbuf[2][32][132];          // 33.8 KB (exact hi+lo values)
    __shared__ float tmpv[64][132];              // 33.8 KB
    __shared__ unsigned short medb[64][132];     // 16.9 KB
    __shared__ float exmed[8][132];              //  4.2 KB
    __shared__ float w2l[128][9];                //  4.6 KB
    __shared__ float rowacc[64][4];
    __shared__ float rowstat[64][4];

    const int tid = threadIdx.x;
    const int tile = blockIdx.x;
    const int row0 = tile * 64;
    const int b = row0 >> 9, l0 = row0 & (NL - 1);
    const bool exact = (l0 == 0);

    auto stagechunk = [&](int uv, int cb, int dst) {
        for (int i = tid; i < 88 * 128; i += 1024) {
            int si = i >> 7, cc = i & 127;
            int lc = l0 - 12 + si;
            lc = lc < 0 ? 0 : (lc > NL - 1 ? NL - 1 : lc);
            unsigned short h = C[(size_t)(b * NL + lc) * CW + uv * NH + cb + cc];
            stg[dst][si][cc] = h;
            if (exact && si < 32) {
                float lo = bf2f(Clo[((size_t)b * 20 + lc) * CW + uv * NH + cb + cc]);
                exbuf[dst][si][cc] = bf2f(h) + lo;
            }
        }
    };
    auto rv = [&](int dst, int si, int cc) -> float {
        if (exact && si < 32) return exbuf[dst][si][cc];
        return bf2f(stg[dst][si][cc]);
    };

    if (tid < 256) rowacc[tid >> 2][tid & 3] = 0.f;

    // ---- phase A: LN stats ----
    for (int hc = 0; hc < 16; ++hc) {
        int uv = hc >> 3, cb = (hc & 7) * 128;
        __syncthreads();
        stagechunk(uv, cb, 0);
        __syncthreads();
        {
            int cc = tid & 127, rg = tid >> 7;
            int r0 = rg * 8;
            float bias = uv ? bs[cb + cc] : bt[cb + cc];
            float run = 0.f;
            #pragma unroll
            for (int w = 0; w < 25; ++w) run += rv(0, r0 + w, cc);
            for (int r = r0; r < r0 + 8; ++r) {
                if (r > r0) run += rv(0, r + 24, cc) - rv(0, r - 1, cc);
                float ma = run * (1.f / 25.f);
                float v = uv ? (ma + bias) : (rv(0, r + 12, cc) - ma + bias);
                tmpv[r][cc] = v;
            }
        }
        __syncthreads();
        {
            int row = tid >> 4, cg = tid & 15;
            float s = 0.f, q = 0.f;
            #pragma unroll
            for (int i = 0; i < 8; ++i) { float v = tmpv[row][cg * 8 + i]; s += v; q += v * v; }
            #pragma unroll
            for (int o = 1; o < 16; o <<= 1) { s += __shfl_xor(s, o); q += __shfl_xor(q, o); }
            if (cg == 0) { rowacc[row][uv * 2] += s; rowacc[row][uv * 2 + 1] += q; }
        }
    }
    __syncthreads();
    if (tid < 64) {
        float mut = rowacc[tid][0] * (1.f / NH);
        float vt  = rowacc[tid][1] * (1.f / NH) - mut * mut;
        float mus = rowacc[tid][2] * (1.f / NH);
        float vs  = rowacc[tid][3] * (1.f / NH) - mus * mus;
        rowstat[tid][0] = mut; rowstat[tid][1] = rsqrtf(vt + 1e-5f);
        rowstat[tid][2] = mus; rowstat[tid][3] = rsqrtf(vs + 1e-5f);
    }

    // ---- phase B: med + logits ----
    float lg[NE];
    #pragma unroll
    for (int e = 0; e < NE; ++e) lg[e] = 0.f;

    for (int cp = 0; cp < 8; ++cp) {
        __syncthreads();
        stagechunk(0, cp * 128, 0);
        stagechunk(1, cp * 128, 1);
        if (tid < 1024) {
            int hh = tid >> 3, e = tid & 7;
            if (hh < 128) w2l[hh][e] = W2[(size_t)(cp * 128 + hh) * NE + e];
        }
        __syncthreads();
        {
            int cc = tid & 127, rg = tid >> 7;
            int r0 = rg * 8;
            int h = cp * 128 + cc;
            float btv = bt[h], bsv = bs[h];
            float gtv = gt[h], betv = bet[h], gsv = gs[h], besv = bes[h];
            float runU = 0.f, runV = 0.f;
            #pragma unroll
            for (int w = 0; w < 25; ++w) { runU += rv(0, r0 + w, cc); runV += rv(1, r0 + w, cc); }
            for (int r = r0; r < r0 + 8; ++r) {
                if (r > r0) {
                    runU += rv(0, r + 24, cc) - rv(0, r - 1, cc);
                    runV += rv(1, r + 24, cc) - rv(1, r - 1, cc);
                }
                float maU = runU * (1.f / 25.f), maV = runV * (1.f / 25.f);
                float tpre = rv(0, r + 12, cc) - maU + btv;
                float spre = maV + bsv;
                float tn = (tpre - rowstat[r][0]) * rowstat[r][1] * gtv + betv;
                float sn = (spre - rowstat[r][2]) * rowstat[r][3] * gsv + besv;
                float m = tn + sn; m = m > 0.f ? m : 0.f;
                medb[r][cc] = f2bf(m);
                if (exact && r < 8) exmed[r][cc] = m;
            }
        }
        __syncthreads();
        {
            int row = tid >> 4, cg = tid & 15;
            #pragma unroll
            for (int i = 0; i < 8; ++i) {
                int hl = cg * 8 + i;
                float m = (exact && row < 8) ? exmed[row][hl] : bf2f(medb[row][hl]);
                #pragma unroll
                for (int e = 0; e < NE; ++e) lg[e] = fmaf(m, w2l[hl][e], lg[e]);
            }
        }
    }

    #pragma unroll
    for (int o = 1; o < 16; o <<= 1)
        #pragma unroll
        for (int e = 0; e < NE; ++e) lg[e] += __shfl_xor(lg[e], o);

    if ((tid & 15) == 0) {
        int row = tid >> 4;
        #pragma unroll
        for (int e = 0; e < NE; ++e) lg[e] += b2[e];
        float mx = lg[0];
        #pragma unroll
        for (int e = 1; e < NE; ++e) mx = lg[e] > mx ? lg[e] : mx;
        float p[NE]; float sum = 0.f;
        #pragma unroll
        for (int e = 0; e < NE; ++e) { p[e] = expf(lg[e] - mx); sum += p[e]; }
        float inv = 1.f / sum;
        int i0 = 0;
        #pragma unroll
        for (int e = 1; e < NE; ++e) if (lg[e] > lg[i0]) i0 = e;
        int i1 = i0 == 0 ? 1 : 0;
        #pragma unroll
        for (int e = 0; e < NE; ++e) if (e != i0 && lg[e] > lg[i1]) i1 = e;
        atomicOr(&mb[2 * b + 0], 1u << i0);
        atomicOr(&mb[2 * b + 1], 1u << i1);
        if (exact && row < 8) {
            #pragma unroll
            for (int e = 0; e < NE; ++e)
                gates[((size_t)b * 8 + row) * NE + e] = p[e] * inv;
        }
    }
}

// masked = gates * maskbit; denom = sum_b + 1e-4; out = masked/denom*64
__global__ void finalize_k(const unsigned* __restrict__ mb,
                           const float* __restrict__ gates,
                           float* __restrict__ out)
{
    int t = threadIdx.x;
    if (t >= 16) return;
    int l = t >> 1, e = t & 1;
    float m[NB];
    float sum = 0.f;
    #pragma unroll
    for (int bb = 0; bb < NB; ++bb) {
        float gvv = gates[((size_t)bb * 8 + l) * NE + e];
        float on  = ((mb[2 * bb + e] >> l) & 1u) ? 1.f : 0.f;
        m[bb] = gvv * on;
        sum += m[bb];
    }
    float scale = 64.f / (sum + 1e-4f);   // capacity = int(2.0*32)
    #pragma unroll
    for (int bb = 0; bb < NB; ++bb)
        out[(size_t)bb * (NL * NE) + l * NE + e] = m[bb] * scale;
}

extern "C" void kernel_launch(void* const* d_in, const int* in_sizes, int n_in,
                              void* d_out, int out_size, void* d_ws, size_t ws_size,
                              hipStream_t stream) {
    const float* x   = (const float*)d_in[0];
    const float* Wt  = (const float*)d_in[1];
    const float* bt  = (const float*)d_in[2];
    const float* gt  = (const float*)d_in[3];
    const float* bet = (const float*)d_in[4];
    const float* Ws  = (const float*)d_in[5];
    const float* bs  = (const float*)d_in[6];
    const float* gs  = (const float*)d_in[7];
    const float* bes = (const float*)d_in[8];
    const float* W2  = (const float*)d_in[9];
    const float* b2  = (const float*)d_in[10];
    float* out = (float*)d_out;

    char* wsb = (char*)d_ws;
    unsigned*       mbp   = (unsigned*)wsb;                            // 256 B
    float*          gates = (float*)(wsb + 256);                       // 2 KB
    unsigned*       bpack = (unsigned*)(wsb + 4096);                   // 4 MiB
    unsigned short* C     = (unsigned short*)(wsb + 4096 + 4194304);   // 64 MiB
    unsigned short* Clo   = (unsigned short*)(wsb + 4096 + 4194304 + (size_t)NROWS * CW * 2);  // 2.5 MiB

    hipMemsetAsync(d_out, 0, sizeof(float) * NB * NL * NE, stream);
    hipMemsetAsync(mbp, 0, 256, stream);

    wprep<<<256, 256, 0, stream>>>(Wt, Ws, bpack);
    gemm_uv<<<2048, 256, 0, stream>>>(x, bpack, C, Clo);
    stage2<<<256, 1024, 0, stream>>>(C, Clo, bt, gt, bet, bs, gs, bes, W2, b2, mbp, gates);
    finalize_k<<<1, 64, 0, stream>>>(mbp, gates, out);
}